// Round 11
// baseline (45.159 us; speedup 1.0000x reference)
//
#include <hip/hip_runtime.h>

// ConvSurface: out[m,f,k] = max_s relu( (point_{m,f,s} - center_{m,f}) . W_k + b_k )
// Lane = kernel k (64 = wave64). One wave per FACE, m-loop over 8 meshes.
// R11: exactly R4 (the best clean variant, 31.8us: corners/centers/beta/gamma
// all on the scalar SMEM path, broadcast via the FMA's SGPR operand slot)
// with ONE change: __launch_bounds__(256,8). R4's counters showed per-wave
// VALU duty ~9% (8 SMEM drain windows per wave) and only ~4 waves/SIMD ->
// VALUBusy 35%. Doubling resident waves/SIMD to 8 overlaps 8 independent
// drain windows -> predicted VALUBusy ~60-75%, dur ~16-22us. VGPR=20 (<64
// cap at 8 waves/EU) so no spill risk; SGPRs are per-wave on gfx9+.
// Algebra: alpha+beta+gamma==1 => p.W = a1 + beta*(a2-a1) + gamma*(a3-a1);
// bias/center-dot/relu folded outside the sample max (monotone).

#define NM 8
#define NF 16384
#define NK 64

__global__ __launch_bounds__(256, 8) void conv_surface_kernel(
    const float* __restrict__ centers,   // [M,F,3]
    const float* __restrict__ nc,        // [M,F,3,3,3]
    const float* __restrict__ beta,      // [F,24]
    const float* __restrict__ gammav,    // [F,24]
    const float* __restrict__ W,         // [64,3]
    const float* __restrict__ b,         // [64]
    float* __restrict__ out)             // [M,F,64]
{
    const int lane = threadIdx.x & 63;
    // wave id into SGPR so all face-level addresses are provably uniform
    const int wav  = __builtin_amdgcn_readfirstlane((int)(threadIdx.x >> 6));
    const int f    = blockIdx.x * 4 + wav;          // face id

    // per-lane kernel weights (tiny, L1-resident)
    const float w0 = W[lane * 3 + 0];
    const float w1 = W[lane * 3 + 1];
    const float w2 = W[lane * 3 + 2];
    const float bk = b[lane];

    // face sample coefficients: wave-uniform scalar loads, resident in SGPRs,
    // loaded once and reused for all 8 meshes
    const float4* __restrict__ bp4 = (const float4*)(beta   + (size_t)f * 24);
    const float4* __restrict__ gp4 = (const float4*)(gammav + (size_t)f * 24);
    float bs[24], gs[24];
#pragma unroll
    for (int q = 0; q < 6; ++q) {
        const float4 bv = bp4[q];
        const float4 gv = gp4[q];
        bs[q * 4 + 0] = bv.x; bs[q * 4 + 1] = bv.y; bs[q * 4 + 2] = bv.z; bs[q * 4 + 3] = bv.w;
        gs[q * 4 + 0] = gv.x; gs[q * 4 + 1] = gv.y; gs[q * 4 + 2] = gv.z; gs[q * 4 + 3] = gv.w;
    }

#pragma unroll 2
    for (int m = 0; m < NM; ++m) {
        const size_t gidx = (size_t)m * NF + f;

        const float* __restrict__ cp = centers + gidx * 3;
        const float cdot = cp[0] * w0 + cp[1] * w1 + cp[2] * w2;

        const float* __restrict__ tp = nc + gidx * 27;
        float nmax[3];
#pragma unroll
        for (int n = 0; n < 3; ++n) {
            const float* __restrict__ t = tp + n * 9;
            const float a1 = t[0] * w0 + t[1] * w1 + t[2] * w2;
            const float a2 = t[3] * w0 + t[4] * w1 + t[5] * w2;
            const float a3 = t[6] * w0 + t[7] * w1 + t[8] * w2;
            const float e2 = a2 - a1;
            const float e3 = a3 - a1;

            // 8 samples of this neighbor: independent FMAs, max3-friendly tree
            float v[8];
#pragma unroll
            for (int j = 0; j < 8; ++j) {
                const int s = n + 3 * j;              // reference order: n = s%3
                v[j] = fmaf(bs[s], e2, fmaf(gs[s], e3, a1));
            }
            const float m0 = fmaxf(fmaxf(v[0], v[1]), v[2]);
            const float m1 = fmaxf(fmaxf(v[3], v[4]), v[5]);
            const float m2 = fmaxf(fmaxf(v[6], v[7]), m0);
            nmax[n] = fmaxf(m1, m2);
        }
        const float mx = fmaxf(fmaxf(nmax[0], nmax[1]), nmax[2]);

        out[gidx * NK + lane] = fmaxf(mx + (bk - cdot), 0.0f);
    }
}

extern "C" void kernel_launch(void* const* d_in, const int* in_sizes, int n_in,
                              void* d_out, int out_size, void* d_ws, size_t ws_size,
                              hipStream_t stream) {
    const float* centers = (const float*)d_in[0];
    // d_in[1] = ring_n  (unused by the reference math)
    const float* nc      = (const float*)d_in[2];
    // d_in[3] = alpha   (unused: alpha = 1 - beta - gamma)
    const float* beta    = (const float*)d_in[4];
    const float* gammav  = (const float*)d_in[5];
    const float* W       = (const float*)d_in[6];
    const float* b       = (const float*)d_in[7];
    float* out = (float*)d_out;

    dim3 grid(NF / 4), block(256);   // one wave per face, 8 meshes per wave
    hipLaunchKernelGGL(conv_surface_kernel, grid, block, 0, stream,
                       centers, nc, beta, gammav, W, b, out);
}

// Round 12
// 36.628 us; speedup vs baseline: 1.2329x; 1.2329x over previous
//
#include <hip/hip_runtime.h>

// ConvSurface: out[m,f,k] = max_s relu( (point_{m,f,s} - center_{m,f}) . W_k + b_k )
// Lane = kernel k (64 = wave64). One wave per FACE.
// R12: loop-nest swap. Session model: SMEM->SGPR broadcast is the only
// efficient path for wave-uniform data (R7/R9 VMEM: compiler sinks loads;
// R10 readlane: VALU tax; R5/R6/R8: >64 live VGPRs = catastrophic spill;
// R11: >4 waves/EU thrashes the per-CU scalar cache). R4's limit was SGPR
// pressure: beta/gamma(48) + corners left room for only ~1 mesh of corner
// loads -> 8 serial drain windows per wave, duty ~9%.
// Swap: outer loop over neighbor n (3), inner over meshes (8). Resident set
// becomes bn/gn (16 dwords, this neighbor only) + ALL 8 meshes' corner rows
// for this neighbor (72 dwords) = ~102 SGPRs -> fits. Per neighbor: one
// batched load volley, ONE lgkm drain, then 8 meshes x ~33 VALU of pure
// compute. 3 big windows/wave instead of 8 small ones.
// Per-lane state: mx[8] + cdot[8] + weights ~= 36 VGPR, safely under the
// 64-VGPR spill cliff. Occupancy kept at the proven (256,4).
// Algebra: alpha+beta+gamma==1 => p.W = a1 + beta*(a2-a1) + gamma*(a3-a1);
// bias/center-dot/relu folded outside the sample max (monotone).

#define NM 8
#define NF 16384
#define NK 64

__global__ __launch_bounds__(256, 4) void conv_surface_kernel(
    const float* __restrict__ centers,   // [M,F,3]
    const float* __restrict__ nc,        // [M,F,3,3,3]
    const float* __restrict__ beta,      // [F,24]
    const float* __restrict__ gammav,    // [F,24]
    const float* __restrict__ W,         // [64,3]
    const float* __restrict__ b,         // [64]
    float* __restrict__ out)             // [M,F,64]
{
    const int lane = threadIdx.x & 63;
    // wave id into SGPR so all face-level addresses are provably uniform
    const int wav  = __builtin_amdgcn_readfirstlane((int)(threadIdx.x >> 6));
    const int f    = blockIdx.x * 4 + wav;          // face id

    // per-lane kernel weights (tiny, L1-resident)
    const float w0 = W[lane * 3 + 0];
    const float w1 = W[lane * 3 + 1];
    const float w2 = W[lane * 3 + 2];
    const float bk = b[lane];

    // prologue: centers (24 uniform dwords -> SGPRs) folded to per-lane cdot
    float cdot[NM], mx[NM];
#pragma unroll
    for (int m = 0; m < NM; ++m) {
        const float* __restrict__ cp = centers + ((size_t)m * NF + f) * 3;
        cdot[m] = cp[0] * w0 + cp[1] * w1 + cp[2] * w2;
        mx[m]   = -3.4e38f;
    }

#pragma unroll
    for (int n = 0; n < 3; ++n) {
        // this neighbor's sample coefficients: 16 uniform dwords (s = n+3j)
        float bn[8], gn[8];
#pragma unroll
        for (int j = 0; j < 8; ++j) {
            bn[j] = beta  [(size_t)f * 24 + n + 3 * j];
            gn[j] = gammav[(size_t)f * 24 + n + 3 * j];
        }

        // ALL 8 meshes' corner rows for this neighbor: 72 uniform dwords,
        // batched ahead of the compute so they drain once
        float ta[NM][9];
#pragma unroll
        for (int m = 0; m < NM; ++m) {
            const float* __restrict__ t = nc + ((size_t)m * NF + f) * 27 + n * 9;
#pragma unroll
            for (int e = 0; e < 9; ++e) ta[m][e] = t[e];
        }

        // compute: 8 meshes of pure VALU (no loads inside)
#pragma unroll
        for (int m = 0; m < NM; ++m) {
            const float a1 = ta[m][0] * w0 + ta[m][1] * w1 + ta[m][2] * w2;
            const float a2 = ta[m][3] * w0 + ta[m][4] * w1 + ta[m][5] * w2;
            const float a3 = ta[m][6] * w0 + ta[m][7] * w1 + ta[m][8] * w2;
            const float e2 = a2 - a1;
            const float e3 = a3 - a1;

            const float v0 = fmaf(bn[0], e2, fmaf(gn[0], e3, a1));
            const float v1 = fmaf(bn[1], e2, fmaf(gn[1], e3, a1));
            const float v2 = fmaf(bn[2], e2, fmaf(gn[2], e3, a1));
            const float v3 = fmaf(bn[3], e2, fmaf(gn[3], e3, a1));
            const float v4 = fmaf(bn[4], e2, fmaf(gn[4], e3, a1));
            const float v5 = fmaf(bn[5], e2, fmaf(gn[5], e3, a1));
            const float v6 = fmaf(bn[6], e2, fmaf(gn[6], e3, a1));
            const float v7 = fmaf(bn[7], e2, fmaf(gn[7], e3, a1));

            const float p0 = fmaxf(fmaxf(v0, v1), v2);   // max3-friendly
            const float p1 = fmaxf(fmaxf(v3, v4), v5);
            const float p2 = fmaxf(fmaxf(v6, v7), p0);
            mx[m] = fmaxf(mx[m], fmaxf(p1, p2));
        }
    }

    // epilogue: fold bias/center-dot/relu, coalesced 256B stores per wave
#pragma unroll
    for (int m = 0; m < NM; ++m)
        out[((size_t)m * NF + f) * NK + lane] = fmaxf(mx[m] + (bk - cdot[m]), 0.0f);
}

extern "C" void kernel_launch(void* const* d_in, const int* in_sizes, int n_in,
                              void* d_out, int out_size, void* d_ws, size_t ws_size,
                              hipStream_t stream) {
    const float* centers = (const float*)d_in[0];
    // d_in[1] = ring_n  (unused by the reference math)
    const float* nc      = (const float*)d_in[2];
    // d_in[3] = alpha   (unused: alpha = 1 - beta - gamma)
    const float* beta    = (const float*)d_in[4];
    const float* gammav  = (const float*)d_in[5];
    const float* W       = (const float*)d_in[6];
    const float* b       = (const float*)d_in[7];
    float* out = (float*)d_out;

    dim3 grid(NF / 4), block(256);   // one wave per face, 8 meshes per wave
    hipLaunchKernelGGL(conv_surface_kernel, grid, block, 0, stream,
                       centers, nc, beta, gammav, W, b, out);
}